// Round 7
// baseline (100.615 us; speedup 1.0000x reference)
//
#include <hip/hip_runtime.h>

#define NUM_CLASSES 21
#define CCH 256          // channels
#define HW (128 * 128)   // pixels per image
#define BATCH 16
#define THREADS 256
#define PPT 4                               // pixels per thread (float4 loads)
#define PIX_PER_BLOCK (THREADS * PPT)       // 1024
#define PIX_CHUNKS (HW / PIX_PER_BLOCK)     // 16
#define CSPLIT 8
#define CBLK (CCH / CSPLIT)                 // 32 channels per block
#define PSTRIDE (NUM_CLASSES + 1)           // 22: col 21 = zero column for ignore-label
#define GRID (BATCH * PIX_CHUNKS * CSPLIT)  // 2048 blocks -> 8 blocks/CU -> 32 waves/CU

// ws layout (floats): qsum[21] | dsum[21] | cnt[21] | counter(u32 at [63])

__global__ __launch_bounds__(THREADS) void fcl_fused_kernel(
    const float* __restrict__ feat, const int* __restrict__ labels,
    const float* __restrict__ proto, float* __restrict__ ws,
    float* __restrict__ out)
{
    __shared__ float protoT[CBLK][PSTRIDE];
    __shared__ float binsQ[NUM_CLASSES];
    __shared__ float binsD[NUM_CLASSES];
    __shared__ int   binsC[NUM_CLASSES];
    __shared__ bool  isLast;
    __shared__ float perClass[NUM_CLASSES];

    const int bid = blockIdx.x;
    const int cb  = bid % CSPLIT;                    // channel slice
    const int pc  = (bid / CSPLIT) % PIX_CHUNKS;     // pixel chunk
    const int b   = bid / (CSPLIT * PIX_CHUNKS);     // batch
    const int c0  = cb * CBLK;

    // Stage transposed prototype slice: protoT[ci][cls] = proto[cls*C + c0+ci]
    for (int idx = threadIdx.x; idx < CBLK * NUM_CLASSES; idx += THREADS) {
        int ci = idx / NUM_CLASSES, cls = idx % NUM_CLASSES;
        protoT[ci][cls] = proto[cls * CCH + c0 + ci];
    }
    if (threadIdx.x < CBLK) protoT[threadIdx.x][NUM_CLASSES] = 0.f;
    if (threadIdx.x < NUM_CLASSES) {
        binsQ[threadIdx.x] = 0.f; binsD[threadIdx.x] = 0.f; binsC[threadIdx.x] = 0;
    }
    __syncthreads();

    const int pix0 = pc * PIX_PER_BLOCK + threadIdx.x * PPT;
    const int4 lv = *reinterpret_cast<const int4*>(labels + b * HW + pix0);
    int l0 = lv.x, l1 = lv.y, l2 = lv.z, l3 = lv.w;
    const bool v0 = (l0 != 255), v1 = (l1 != 255), v2 = (l2 != 255), v3 = (l3 != 255);
    if (!v0) l0 = NUM_CLASSES;   // zero column -> d contribution 0
    if (!v1) l1 = NUM_CLASSES;
    if (!v2) l2 = NUM_CLASSES;
    if (!v3) l3 = NUM_CLASSES;

    const float* fb = feat + ((size_t)b * CCH + c0) * HW + pix0;

    float q0 = 0.f, q1 = 0.f, q2 = 0.f, q3 = 0.f;
    float d0 = 0.f, d1 = 0.f, d2 = 0.f, d3 = 0.f;

#pragma unroll 8
    for (int ci = 0; ci < CBLK; ci++) {
        float4 f = *reinterpret_cast<const float4*>(fb + (size_t)ci * HW);
        float p0 = protoT[ci][l0];
        float p1 = protoT[ci][l1];
        float p2 = protoT[ci][l2];
        float p3 = protoT[ci][l3];
        q0 = fmaf(f.x, f.x, q0);  d0 = fmaf(f.x, p0, d0);
        q1 = fmaf(f.y, f.y, q1);  d1 = fmaf(f.y, p1, d1);
        q2 = fmaf(f.z, f.z, q2);  d2 = fmaf(f.z, p2, d2);
        q3 = fmaf(f.w, f.w, q3);  d3 = fmaf(f.w, p3, d3);
    }

    // Per-block class binning in LDS
    if (v0) { atomicAdd(&binsQ[l0], q0); atomicAdd(&binsD[l0], d0); }
    if (v1) { atomicAdd(&binsQ[l1], q1); atomicAdd(&binsD[l1], d1); }
    if (v2) { atomicAdd(&binsQ[l2], q2); atomicAdd(&binsD[l2], d2); }
    if (v3) { atomicAdd(&binsQ[l3], q3); atomicAdd(&binsD[l3], d3); }
    if (cb == 0) {   // count each pixel exactly once (channel-slice 0 only)
        if (v0) atomicAdd(&binsC[l0], 1);
        if (v1) atomicAdd(&binsC[l1], 1);
        if (v2) atomicAdd(&binsC[l2], 1);
        if (v3) atomicAdd(&binsC[l3], 1);
    }
    __syncthreads();

    // Global accumulation (device-scope atomics, coherent at the memory side)
    if (threadIdx.x < NUM_CLASSES) {
        atomicAdd(&ws[threadIdx.x], binsQ[threadIdx.x]);
        atomicAdd(&ws[NUM_CLASSES + threadIdx.x], binsD[threadIdx.x]);
        if (cb == 0)
            atomicAdd(&ws[2 * NUM_CLASSES + threadIdx.x], (float)binsC[threadIdx.x]);
    }

    // NO __threadfence() (R3/R4: per-block fence = L2 writeback storm, 5-6x).
    // __syncthreads() emits s_waitcnt vmcnt(0) before s_barrier, so this
    // block's ws atomics are complete at the coherence point before thread 0
    // increments the counter.
    __syncthreads();
    if (threadIdx.x == 0) {
        unsigned int old = atomicAdd(reinterpret_cast<unsigned int*>(ws + 63), 1u);
        isLast = (old == GRID - 1);
    }
    __syncthreads();
    if (!isLast) return;

    // Last block: read partials with atomic RMWs (fetch from coherence point).
    const int t = threadIdx.x;
    if (t < NUM_CLASSES) {
        float qsum = atomicAdd(&ws[t], 0.f);
        float dsum = atomicAdd(&ws[NUM_CLASSES + t], 0.f);
        float cnt  = atomicAdd(&ws[2 * NUM_CLASSES + t], 0.f);
        // P2[t] = sum_c proto[t][c]^2 (4 partials to break dep chain)
        const float* pr = proto + t * CCH;
        float s0 = 0.f, s1 = 0.f, s2 = 0.f, s3 = 0.f;
#pragma unroll 4
        for (int i = 0; i < CCH; i += 4) {
            s0 = fmaf(pr[i],   pr[i],   s0);
            s1 = fmaf(pr[i+1], pr[i+1], s1);
            s2 = fmaf(pr[i+2], pr[i+2], s2);
            s3 = fmaf(pr[i+3], pr[i+3], s3);
        }
        float P2 = (s0 + s1) + (s2 + s3);
        perClass[t] = (cnt > 0.f)
            ? (qsum - 2.f * dsum + cnt * P2) / (cnt * (float)CCH)
            : -1.f;   // sentinel: class absent
    }
    __syncthreads();
    if (t == 0) {
        float total = 0.f, npres = 0.f;
        for (int cls = 0; cls < NUM_CLASSES; cls++) {
            float v = perClass[cls];
            if (v != -1.f) { total += v; npres += 1.f; }
        }
        if (npres < 1.f) npres = 1.f;
        out[0] = total / npres;   // FACTOR = 1.0
    }
}

extern "C" void kernel_launch(void* const* d_in, const int* in_sizes, int n_in,
                              void* d_out, int out_size, void* d_ws, size_t ws_size,
                              hipStream_t stream) {
    const float* feat   = (const float*)d_in[0];
    const int*   labels = (const int*)d_in[1];
    const float* proto  = (const float*)d_in[2];
    float* out = (float*)d_out;
    float* ws  = (float*)d_ws;

    (void)in_sizes; (void)n_in; (void)out_size; (void)ws_size;

    (void)hipMemsetAsync(ws, 0, 64 * sizeof(float), stream);
    fcl_fused_kernel<<<GRID, THREADS, 0, stream>>>(feat, labels, proto, ws, out);
}

// Round 8
// 69.396 us; speedup vs baseline: 1.4499x; 1.4499x over previous
//
#include <hip/hip_runtime.h>

#define NUM_CLASSES 21
#define CCH 256          // channels
#define HW (128 * 128)   // pixels per image
#define BATCH 16
#define THREADS 256
#define PPT 4                               // pixels per thread (float4 loads)
#define PIX_PER_BLOCK (THREADS * PPT)       // 1024
#define PIX_CHUNKS (HW / PIX_PER_BLOCK)     // 16
#define CSPLIT 4
#define CBLK (CCH / CSPLIT)                 // 64 channels per block
#define PSTRIDE (NUM_CLASSES + 1)           // 22: col 21 = zero column for ignore-label
#define GRID (BATCH * PIX_CHUNKS * CSPLIT)  // 1024 blocks
#define SLOT 64                             // floats per block slot in ws

// ws layout: GRID slots of 64 floats. slot[b][0..20]=Q, [21..41]=D, [42..62]=C.
// Every slot is fully rewritten every call -> no zeroing, no atomics, no counter.

__global__ __launch_bounds__(THREADS) void fcl_main_kernel(
    const float* __restrict__ feat, const int* __restrict__ labels,
    const float* __restrict__ proto, float* __restrict__ ws)
{
    __shared__ float protoT[CBLK][PSTRIDE];
    __shared__ float binsQ[NUM_CLASSES];
    __shared__ float binsD[NUM_CLASSES];
    __shared__ int   binsC[NUM_CLASSES];

    const int bid = blockIdx.x;
    const int cb  = bid % CSPLIT;                    // channel slice
    const int pc  = (bid / CSPLIT) % PIX_CHUNKS;     // pixel chunk
    const int b   = bid / (CSPLIT * PIX_CHUNKS);     // batch
    const int c0  = cb * CBLK;

    // Stage transposed prototype slice: protoT[ci][cls] = proto[cls*C + c0+ci]
    for (int idx = threadIdx.x; idx < CBLK * NUM_CLASSES; idx += THREADS) {
        int ci = idx / NUM_CLASSES, cls = idx % NUM_CLASSES;
        protoT[ci][cls] = proto[cls * CCH + c0 + ci];
    }
    if (threadIdx.x < CBLK) protoT[threadIdx.x][NUM_CLASSES] = 0.f;
    if (threadIdx.x < NUM_CLASSES) {
        binsQ[threadIdx.x] = 0.f; binsD[threadIdx.x] = 0.f; binsC[threadIdx.x] = 0;
    }
    __syncthreads();

    const int pix0 = pc * PIX_PER_BLOCK + threadIdx.x * PPT;
    const int4 lv = *reinterpret_cast<const int4*>(labels + b * HW + pix0);
    int l0 = lv.x, l1 = lv.y, l2 = lv.z, l3 = lv.w;
    const bool v0 = (l0 != 255), v1 = (l1 != 255), v2 = (l2 != 255), v3 = (l3 != 255);
    if (!v0) l0 = NUM_CLASSES;   // zero column -> d contribution 0
    if (!v1) l1 = NUM_CLASSES;
    if (!v2) l2 = NUM_CLASSES;
    if (!v3) l3 = NUM_CLASSES;

    const float* fb = feat + ((size_t)b * CCH + c0) * HW + pix0;

    float q0 = 0.f, q1 = 0.f, q2 = 0.f, q3 = 0.f;
    float d0 = 0.f, d1 = 0.f, d2 = 0.f, d3 = 0.f;

#pragma unroll 8
    for (int ci = 0; ci < CBLK; ci++) {
        float4 f = *reinterpret_cast<const float4*>(fb + (size_t)ci * HW);
        float p0 = protoT[ci][l0];
        float p1 = protoT[ci][l1];
        float p2 = protoT[ci][l2];
        float p3 = protoT[ci][l3];
        q0 = fmaf(f.x, f.x, q0);  d0 = fmaf(f.x, p0, d0);
        q1 = fmaf(f.y, f.y, q1);  d1 = fmaf(f.y, p1, d1);
        q2 = fmaf(f.z, f.z, q2);  d2 = fmaf(f.z, p2, d2);
        q3 = fmaf(f.w, f.w, q3);  d3 = fmaf(f.w, p3, d3);
    }

    // Per-block class binning in LDS (LDS atomics only)
    if (v0) { atomicAdd(&binsQ[l0], q0); atomicAdd(&binsD[l0], d0); }
    if (v1) { atomicAdd(&binsQ[l1], q1); atomicAdd(&binsD[l1], d1); }
    if (v2) { atomicAdd(&binsQ[l2], q2); atomicAdd(&binsD[l2], d2); }
    if (v3) { atomicAdd(&binsQ[l3], q3); atomicAdd(&binsD[l3], d3); }
    if (cb == 0) {   // count each pixel exactly once (channel-slice 0 only)
        if (v0) atomicAdd(&binsC[l0], 1);
        if (v1) atomicAdd(&binsC[l1], 1);
        if (v2) atomicAdd(&binsC[l2], 1);
        if (v3) atomicAdd(&binsC[l3], 1);
    }
    __syncthreads();

    // NO global atomics (R7: same-address RMW chains scale with block count
    // and serialize at the coherence point). Private slot per block, one
    // coalesced 63-lane store. Slots fully rewritten every call.
    if (threadIdx.x < 63) {
        float v = (threadIdx.x < NUM_CLASSES) ? binsQ[threadIdx.x]
                : (threadIdx.x < 2 * NUM_CLASSES) ? binsD[threadIdx.x - NUM_CLASSES]
                : (float)binsC[threadIdx.x - 2 * NUM_CLASSES];
        ws[(size_t)bid * SLOT + threadIdx.x] = v;
    }
}

__global__ __launch_bounds__(512) void fcl_reduce_kernel(
    const float* __restrict__ proto, const float* __restrict__ ws,
    float* __restrict__ out)
{
    __shared__ float red[8][SLOT];       // [group][slot-lane]
    __shared__ float fin[SLOT];
    __shared__ float perClass[NUM_CLASSES];

    const int t   = threadIdx.x;
    const int cls = t & (SLOT - 1);      // 0..63 (63 unused lane reads pad)
    const int g   = t >> 6;              // 0..7

    float s = 0.f;
#pragma unroll 16
    for (int bid = g; bid < GRID; bid += 8)
        s += ws[(size_t)bid * SLOT + cls];
    red[g][cls] = s;
    __syncthreads();

    if (t < SLOT) {
        float tot = 0.f;
#pragma unroll
        for (int i = 0; i < 8; i++) tot += red[i][t];
        fin[t] = tot;
    }
    __syncthreads();

    if (t < NUM_CLASSES) {
        float qsum = fin[t];
        float dsum = fin[NUM_CLASSES + t];
        float cnt  = fin[2 * NUM_CLASSES + t];
        // P2[t] = sum_c proto[t][c]^2 (4 partials to break dep chain)
        const float* pr = proto + t * CCH;
        float s0 = 0.f, s1 = 0.f, s2 = 0.f, s3 = 0.f;
#pragma unroll 4
        for (int i = 0; i < CCH; i += 4) {
            s0 = fmaf(pr[i],   pr[i],   s0);
            s1 = fmaf(pr[i+1], pr[i+1], s1);
            s2 = fmaf(pr[i+2], pr[i+2], s2);
            s3 = fmaf(pr[i+3], pr[i+3], s3);
        }
        float P2 = (s0 + s1) + (s2 + s3);
        perClass[t] = (cnt > 0.f)
            ? (qsum - 2.f * dsum + cnt * P2) / (cnt * (float)CCH)
            : -1.f;   // sentinel: class absent
    }
    __syncthreads();
    if (t == 0) {
        float total = 0.f, npres = 0.f;
        for (int cls2 = 0; cls2 < NUM_CLASSES; cls2++) {
            float v = perClass[cls2];
            if (v != -1.f) { total += v; npres += 1.f; }
        }
        if (npres < 1.f) npres = 1.f;
        out[0] = total / npres;   // FACTOR = 1.0
    }
}

extern "C" void kernel_launch(void* const* d_in, const int* in_sizes, int n_in,
                              void* d_out, int out_size, void* d_ws, size_t ws_size,
                              hipStream_t stream) {
    const float* feat   = (const float*)d_in[0];
    const int*   labels = (const int*)d_in[1];
    const float* proto  = (const float*)d_in[2];
    float* out = (float*)d_out;
    float* ws  = (float*)d_ws;

    (void)in_sizes; (void)n_in; (void)out_size; (void)ws_size;

    fcl_main_kernel<<<GRID, THREADS, 0, stream>>>(feat, labels, proto, ws);
    fcl_reduce_kernel<<<1, 512, 0, stream>>>(proto, ws, out);
}

// Round 9
// 63.317 us; speedup vs baseline: 1.5891x; 1.0960x over previous
//
#include <hip/hip_runtime.h>

#define NUM_CLASSES 21
#define CCH 256          // channels
#define HW (128 * 128)   // pixels per image
#define BATCH 16
#define THREADS 256
#define PPT 4                               // pixels per thread (float4 loads)
#define PIX_PER_BLOCK (THREADS * PPT)       // 1024
#define PIX_CHUNKS (HW / PIX_PER_BLOCK)     // 16
#define CSPLIT 8
#define CBLK (CCH / CSPLIT)                 // 32 channels per block
#define PSTRIDE (NUM_CLASSES + 1)           // 22: col 21 = zero column for ignore-label
#define GRID (BATCH * PIX_CHUNKS * CSPLIT)  // 2048 blocks -> 8 blocks/CU capacity
#define SLOT 64                             // floats per block slot in ws

// ws layout: GRID slots of 64 floats. slot[b][0..20]=Q, [21..41]=D, [42..62]=C.
// Every slot is fully rewritten every call -> no zeroing, no atomics, no counter.

__global__ __launch_bounds__(THREADS) void fcl_main_kernel(
    const float* __restrict__ feat, const int* __restrict__ labels,
    const float* __restrict__ proto, float* __restrict__ ws)
{
    __shared__ float protoT[CBLK][PSTRIDE];
    __shared__ float binsQ[NUM_CLASSES];
    __shared__ float binsD[NUM_CLASSES];
    __shared__ int   binsC[NUM_CLASSES];

    const int bid = blockIdx.x;
    const int cb  = bid % CSPLIT;                    // channel slice
    const int pc  = (bid / CSPLIT) % PIX_CHUNKS;     // pixel chunk
    const int b   = bid / (CSPLIT * PIX_CHUNKS);     // batch
    const int c0  = cb * CBLK;

    // Stage transposed prototype slice: protoT[ci][cls] = proto[cls*C + c0+ci]
    for (int idx = threadIdx.x; idx < CBLK * NUM_CLASSES; idx += THREADS) {
        int ci = idx / NUM_CLASSES, cls = idx % NUM_CLASSES;
        protoT[ci][cls] = proto[cls * CCH + c0 + ci];
    }
    if (threadIdx.x < CBLK) protoT[threadIdx.x][NUM_CLASSES] = 0.f;
    if (threadIdx.x < NUM_CLASSES) {
        binsQ[threadIdx.x] = 0.f; binsD[threadIdx.x] = 0.f; binsC[threadIdx.x] = 0;
    }
    __syncthreads();

    const int pix0 = pc * PIX_PER_BLOCK + threadIdx.x * PPT;
    const int4 lv = *reinterpret_cast<const int4*>(labels + b * HW + pix0);
    int l0 = lv.x, l1 = lv.y, l2 = lv.z, l3 = lv.w;
    const bool v0 = (l0 != 255), v1 = (l1 != 255), v2 = (l2 != 255), v3 = (l3 != 255);
    if (!v0) l0 = NUM_CLASSES;   // zero column -> d contribution 0
    if (!v1) l1 = NUM_CLASSES;
    if (!v2) l2 = NUM_CLASSES;
    if (!v3) l3 = NUM_CLASSES;

    const float* fb = feat + ((size_t)b * CCH + c0) * HW + pix0;

    float q0 = 0.f, q1 = 0.f, q2 = 0.f, q3 = 0.f;
    float d0 = 0.f, d1 = 0.f, d2 = 0.f, d3 = 0.f;

#pragma unroll 8
    for (int ci = 0; ci < CBLK; ci++) {
        float4 f = *reinterpret_cast<const float4*>(fb + (size_t)ci * HW);
        float p0 = protoT[ci][l0];
        float p1 = protoT[ci][l1];
        float p2 = protoT[ci][l2];
        float p3 = protoT[ci][l3];
        q0 = fmaf(f.x, f.x, q0);  d0 = fmaf(f.x, p0, d0);
        q1 = fmaf(f.y, f.y, q1);  d1 = fmaf(f.y, p1, d1);
        q2 = fmaf(f.z, f.z, q2);  d2 = fmaf(f.z, p2, d2);
        q3 = fmaf(f.w, f.w, q3);  d3 = fmaf(f.w, p3, d3);
    }

    // Per-block class binning in LDS (LDS atomics only)
    if (v0) { atomicAdd(&binsQ[l0], q0); atomicAdd(&binsD[l0], d0); }
    if (v1) { atomicAdd(&binsQ[l1], q1); atomicAdd(&binsD[l1], d1); }
    if (v2) { atomicAdd(&binsQ[l2], q2); atomicAdd(&binsD[l2], d2); }
    if (v3) { atomicAdd(&binsQ[l3], q3); atomicAdd(&binsD[l3], d3); }
    if (cb == 0) {   // count each pixel exactly once (channel-slice 0 only)
        if (v0) atomicAdd(&binsC[l0], 1);
        if (v1) atomicAdd(&binsC[l1], 1);
        if (v2) atomicAdd(&binsC[l2], 1);
        if (v3) atomicAdd(&binsC[l3], 1);
    }
    __syncthreads();

    // NO global atomics (R7/R8: same-address RMW chains serialize at the
    // coherence point, cost scales with block count). Private slot per block.
    if (threadIdx.x < 63) {
        float v = (threadIdx.x < NUM_CLASSES) ? binsQ[threadIdx.x]
                : (threadIdx.x < 2 * NUM_CLASSES) ? binsD[threadIdx.x - NUM_CLASSES]
                : (float)binsC[threadIdx.x - 2 * NUM_CLASSES];
        ws[(size_t)bid * SLOT + threadIdx.x] = v;
    }
}

typedef float vf4 __attribute__((ext_vector_type(4)));

__global__ __launch_bounds__(512) void fcl_reduce_kernel(
    const float* __restrict__ proto, const float* __restrict__ ws,
    float* __restrict__ out)
{
    __shared__ float red[32][SLOT];      // 8 KB: [group][slot-lane]
    __shared__ float fin[SLOT];
    __shared__ float perClass[NUM_CLASSES];

    const int t   = threadIdx.x;
    const int vec = t & 15;              // which float4 of the 64-float slot
    const int grp = t >> 4;              // 0..31

    vf4 acc = {0.f, 0.f, 0.f, 0.f};
#pragma unroll 8
    for (int bid = grp; bid < GRID; bid += 32)
        acc += *reinterpret_cast<const vf4*>(ws + (size_t)bid * SLOT + vec * 4);
    red[grp][vec * 4 + 0] = acc.x;
    red[grp][vec * 4 + 1] = acc.y;
    red[grp][vec * 4 + 2] = acc.z;
    red[grp][vec * 4 + 3] = acc.w;
    __syncthreads();

    if (t < SLOT) {
        float tot = 0.f;
#pragma unroll
        for (int i = 0; i < 32; i++) tot += red[i][t];
        fin[t] = tot;
    }
    __syncthreads();

    if (t < NUM_CLASSES) {
        float qsum = fin[t];
        float dsum = fin[NUM_CLASSES + t];
        float cnt  = fin[2 * NUM_CLASSES + t];
        // P2[t] = sum_c proto[t][c]^2 (4 partials to break dep chain)
        const float* pr = proto + t * CCH;
        float s0 = 0.f, s1 = 0.f, s2 = 0.f, s3 = 0.f;
#pragma unroll 4
        for (int i = 0; i < CCH; i += 4) {
            s0 = fmaf(pr[i],   pr[i],   s0);
            s1 = fmaf(pr[i+1], pr[i+1], s1);
            s2 = fmaf(pr[i+2], pr[i+2], s2);
            s3 = fmaf(pr[i+3], pr[i+3], s3);
        }
        float P2 = (s0 + s1) + (s2 + s3);
        perClass[t] = (cnt > 0.f)
            ? (qsum - 2.f * dsum + cnt * P2) / (cnt * (float)CCH)
            : -1.f;   // sentinel: class absent
    }
    __syncthreads();
    if (t == 0) {
        float total = 0.f, npres = 0.f;
        for (int cls2 = 0; cls2 < NUM_CLASSES; cls2++) {
            float v = perClass[cls2];
            if (v != -1.f) { total += v; npres += 1.f; }
        }
        if (npres < 1.f) npres = 1.f;
        out[0] = total / npres;   // FACTOR = 1.0
    }
}

extern "C" void kernel_launch(void* const* d_in, const int* in_sizes, int n_in,
                              void* d_out, int out_size, void* d_ws, size_t ws_size,
                              hipStream_t stream) {
    const float* feat   = (const float*)d_in[0];
    const int*   labels = (const int*)d_in[1];
    const float* proto  = (const float*)d_in[2];
    float* out = (float*)d_out;
    float* ws  = (float*)d_ws;

    (void)in_sizes; (void)n_in; (void)out_size; (void)ws_size;

    fcl_main_kernel<<<GRID, THREADS, 0, stream>>>(feat, labels, proto, ws);
    fcl_reduce_kernel<<<1, 512, 0, stream>>>(proto, ws, out);
}